// Round 1
// baseline (1212.166 us; speedup 1.0000x reference)
//
#include <hip/hip_runtime.h>
#include <math.h>

#define F 128

// ---------------- row-normalize features: xn = x / max(||x||, eps) ----------
__global__ void k_normalize(const float* __restrict__ x, float* __restrict__ xn, int N) {
  int wid = (blockIdx.x * blockDim.x + threadIdx.x) >> 6;  // one wave per node
  int lane = threadIdx.x & 63;
  if (wid >= N) return;
  const float2* src = (const float2*)(x + (size_t)wid * F);
  float2 v = src[lane];
  float ss = v.x * v.x + v.y * v.y;
#pragma unroll
  for (int m = 32; m >= 1; m >>= 1) ss += __shfl_xor(ss, m);
  float inv = 1.0f / fmaxf(sqrtf(ss), 1e-12f);
  float2 o; o.x = v.x * inv; o.y = v.y * inv;
  ((float2*)(xn + (size_t)wid * F))[lane] = o;
}

// ---------------- per-edge cosine sim + threshold + row segment sums --------
__global__ void k_edge_sim(const float* __restrict__ xn, const int* __restrict__ row,
                           const int* __restrict__ col, float* __restrict__ sim,
                           float* __restrict__ rowsum, float* __restrict__ degf, int E) {
  int g = (blockIdx.x * blockDim.x + threadIdx.x) >> 4;  // 16 lanes per edge
  int l = threadIdx.x & 15;
  if (g >= E) return;
  int r = row[g], c = col[g];
  const float4* a = (const float4*)(xn + (size_t)r * F);
  const float4* b = (const float4*)(xn + (size_t)c * F);
  float4 a0 = a[l * 2], a1 = a[l * 2 + 1];
  float4 b0 = b[l * 2], b1 = b[l * 2 + 1];
  float s = a0.x * b0.x + a0.y * b0.y + a0.z * b0.z + a0.w * b0.w
          + a1.x * b1.x + a1.y * b1.y + a1.z * b1.z + a1.w * b1.w;
#pragma unroll
  for (int m = 8; m >= 1; m >>= 1) s += __shfl_xor(s, m);
  if (l == 0) {
    if (s < 0.1f || r == c) s = 0.0f;
    sim[g] = s;
    if (s > 0.0f) {
      atomicAdd(rowsum + r, s);
      atomicAdd(degf + r, 1.0f);
    }
  }
}

// ---------------- per-edge final weight (+gating) + col degree sum ----------
__global__ void k_edge_weight(const int* __restrict__ row, const int* __restrict__ col,
                              float* __restrict__ simw, const float* __restrict__ rowsum,
                              const float* __restrict__ degf, float* __restrict__ adj,
                              const float* __restrict__ gate, int layer,
                              float* __restrict__ colw, int E) {
  int e = blockIdx.x * blockDim.x + threadIdx.x;
  if (e >= E) return;
  int r = row[e], c = col[e];
  float s = simw[e];
  float rs = rowsum[r];
  float sn = (rs > 0.0f) ? s / rs : 0.0f;
  float w = (r == c) ? 1.0f / (degf[r] + 1.0f) : sn;
  w = expf(w);
  float wc;
  if (layer == 0) { adj[e] = w; wc = w; }
  else { float gg = gate[layer - 1]; wc = gg * adj[e] + (1.0f - gg) * w; }
  simw[e] = wc;
  atomicAdd(colw + c, wc);
}

__global__ void k_dinv(const float* __restrict__ colw, float* __restrict__ dinv, int N) {
  int i = blockIdx.x * blockDim.x + threadIdx.x;
  if (i >= N) return;
  float d = colw[i];
  dinv[i] = (d > 0.0f) ? rsqrtf(d) : 0.0f;
}

__global__ void k_nrm(const int* __restrict__ row, const int* __restrict__ col,
                      const float* __restrict__ w, const float* __restrict__ dinv,
                      float* __restrict__ nrm, int E) {
  int e = blockIdx.x * blockDim.x + threadIdx.x;
  if (e >= E) return;
  nrm[e] = dinv[row[e]] * w[e] * dinv[col[e]];
}

// ---------------- GEMM: out[M,128] = A[M,128] @ W[128,128] ------------------
__global__ void k_gemm128(const float* __restrict__ A, const float* __restrict__ W,
                          float* __restrict__ out, int M) {
  __shared__ float As[16][128];
  int t = threadIdx.x;            // 256 threads
  int j = t & 127;                // output col
  int h = t >> 7;                 // node half 0/1
  int n0 = blockIdx.x * 16;
  for (int i = t; i < 16 * 128; i += 256) {
    int nn = i >> 7, kk = i & 127;
    int gn = n0 + nn;
    As[nn][kk] = (gn < M) ? A[(size_t)gn * 128 + kk] : 0.f;
  }
  __syncthreads();
  float acc[8] = {0, 0, 0, 0, 0, 0, 0, 0};
  int base = h * 8;
  for (int k = 0; k < 128; ++k) {
    float wv = W[k * 128 + j];
#pragma unroll
    for (int i = 0; i < 8; ++i) acc[i] += As[base + i][k] * wv;
  }
#pragma unroll
  for (int i = 0; i < 8; ++i) {
    int gn = n0 + base + i;
    if (gn < M) out[(size_t)gn * 128 + j] = acc[i];
  }
}

// ---------------- GEMM: out[M,40] = A[M,128] @ W[128,40] --------------------
__global__ void k_gemm40(const float* __restrict__ A, const float* __restrict__ W,
                         float* __restrict__ out, int M, int C) {
  __shared__ float As[8][128];
  int t = threadIdx.x;            // 320 threads = 8 nodes x 40 cols
  int n0 = blockIdx.x * 8;
  for (int i = t; i < 8 * 128; i += 320) {
    int nn = i >> 7, kk = i & 127;
    int gn = n0 + nn;
    As[nn][kk] = (gn < M) ? A[(size_t)gn * 128 + kk] : 0.f;
  }
  __syncthreads();
  int nn = t / 40;
  int j = t - nn * 40;
  int gn = n0 + nn;
  if (gn < M) {
    float acc = 0.f;
    for (int k = 0; k < 128; ++k) acc += As[nn][k] * W[k * C + j];
    out[(size_t)gn * C + j] = acc;
  }
}

// ---------------- CSR build: histogram, scan, scatter -----------------------
__global__ void k_hist(const int* __restrict__ col, int* __restrict__ cnt, int E) {
  int e = blockIdx.x * blockDim.x + threadIdx.x;
  if (e < E) atomicAdd(cnt + col[e], 1);
}

__global__ void k_scan1(const int* __restrict__ cnt, int* __restrict__ partial,
                        int* __restrict__ bsum, int N) {
  __shared__ int sm[256];
  int t = threadIdx.x;
  int i = blockIdx.x * 256 + t;
  int val = (i < N) ? cnt[i] : 0;
  sm[t] = val;
  __syncthreads();
  for (int off = 1; off < 256; off <<= 1) {
    int v = (t >= off) ? sm[t - off] : 0;
    __syncthreads();
    sm[t] += v;
    __syncthreads();
  }
  if (i < N) partial[i] = sm[t] - val;  // exclusive
  if (t == 255) bsum[blockIdx.x] = sm[255];
}

__global__ void k_scan2(const int* __restrict__ bsum, int* __restrict__ boffs, int nb) {
  __shared__ int sm[256];
  int t = threadIdx.x;
  int val = (t < nb) ? bsum[t] : 0;
  sm[t] = val;
  __syncthreads();
  for (int off = 1; off < 256; off <<= 1) {
    int v = (t >= off) ? sm[t - off] : 0;
    __syncthreads();
    sm[t] += v;
    __syncthreads();
  }
  if (t < nb) boffs[t] = sm[t] - val;  // exclusive
}

__global__ void k_scan3(const int* __restrict__ partial, const int* __restrict__ boffs,
                        int* __restrict__ offs, int N, int E) {
  int i = blockIdx.x * 256 + threadIdx.x;
  if (i < N) offs[i] = partial[i] + boffs[i >> 8];
  if (i == 0) offs[N] = E;
}

__global__ void k_scatter(const int* __restrict__ col, const int* __restrict__ offs,
                          int* __restrict__ cursor, int* __restrict__ perm, int E) {
  int e = blockIdx.x * blockDim.x + threadIdx.x;
  if (e >= E) return;
  int c = col[e];
  int pos = offs[c] + atomicAdd(cursor + c, 1);
  perm[pos] = e;
}

// ---------------- aggregation (gather over CSR) + bias + relu ---------------
__global__ void k_agg128(const float* __restrict__ hW, const float* __restrict__ nrm,
                         const int* __restrict__ perm, const int* __restrict__ offs,
                         const int* __restrict__ row, const float* __restrict__ bias,
                         float* __restrict__ out, int relu) {
  int c = blockIdx.x, j = threadIdx.x;  // 128 threads
  int p0 = offs[c], p1 = offs[c + 1];
  float acc = bias[j];
  for (int p = p0; p < p1; ++p) {
    int e = perm[p];
    acc += nrm[e] * hW[(size_t)row[e] * 128 + j];
  }
  if (relu) acc = fmaxf(acc, 0.f);
  out[(size_t)c * 128 + j] = acc;
}

// ---------------- final aggregation + bias + log_softmax --------------------
__global__ void k_agg40_lsm(const float* __restrict__ hW, const float* __restrict__ nrm,
                            const int* __restrict__ perm, const int* __restrict__ offs,
                            const int* __restrict__ row, const float* __restrict__ bias,
                            float* __restrict__ out, int C) {
  int c = blockIdx.x, j = threadIdx.x;  // 64 threads (one wave)
  int p0 = offs[c], p1 = offs[c + 1];
  bool act = j < C;
  float acc = act ? bias[j] : 0.f;
  for (int p = p0; p < p1; ++p) {
    int e = perm[p];
    float w = nrm[e];
    int r = row[e];
    if (act) acc += w * hW[(size_t)r * C + j];
  }
  float v = act ? acc : -3.0e38f;
#pragma unroll
  for (int m = 32; m >= 1; m >>= 1) v = fmaxf(v, __shfl_xor(v, m));
  float ex = act ? expf(acc - v) : 0.f;
#pragma unroll
  for (int m = 32; m >= 1; m >>= 1) ex += __shfl_xor(ex, m);
  if (act) out[(size_t)c * C + j] = acc - v - logf(ex);
}

extern "C" void kernel_launch(void* const* d_in, const int* in_sizes, int n_in,
                              void* d_out, int out_size, void* d_ws, size_t ws_size,
                              hipStream_t stream) {
  const float* x    = (const float*)d_in[0];
  const float* gate = (const float*)d_in[1];
  const float* W0   = (const float*)d_in[2];
  const float* b0   = (const float*)d_in[3];
  const float* W1   = (const float*)d_in[4];
  const float* b1   = (const float*)d_in[5];
  const float* W2   = (const float*)d_in[6];
  const float* b2   = (const float*)d_in[7];
  const int* eidx   = (const int*)d_in[8];
  int N = in_sizes[0] / 128;
  int E = in_sizes[8] / 2;
  int C = in_sizes[7];  // 40
  const int* row = eidx;
  const int* col = eidx + E;

  char* ws = (char*)d_ws;
  size_t off = 0;
  auto alloc = [&](size_t bytes) {
    char* p = ws + off;
    off += (bytes + 255) & ~(size_t)255;
    return p;
  };
  float* bufA   = (float*)alloc((size_t)N * 128 * 4);  // xn (normalized feats)
  float* bufB   = (float*)alloc((size_t)N * 128 * 4);  // hW (gemm out)
  float* bufC   = (float*)alloc((size_t)N * 128 * 4);  // h  (layer activations)
  float* adj    = (float*)alloc((size_t)E * 4);        // layer-0 weights (kept)
  float* simw   = (float*)alloc((size_t)E * 4);        // sim, then gated weight
  float* nrm    = (float*)alloc((size_t)E * 4);        // dinv[r]*w*dinv[c]
  int*   perm   = (int*)alloc((size_t)E * 4);          // CSR-by-col permutation
  int*   cnt    = (int*)alloc((size_t)N * 4 * 2);      // cnt + cursor (one memset)
  int*   cursor = cnt + N;
  int*   offs   = (int*)alloc((size_t)(N + 1) * 4);
  int*   partial= (int*)alloc((size_t)N * 4);
  int*   bsum   = (int*)alloc(1024);
  int*   boffs  = (int*)alloc(1024);
  float* rowsum = (float*)alloc((size_t)N * 4 * 3);    // rowsum, degf, colw (one memset)
  float* degf   = rowsum + N;
  float* colw   = degf + N;
  float* dinv   = (float*)alloc((size_t)N * 4);

  int nb = (N + 255) / 256;
  int eb = (E + 255) / 256;

  // ---- CSR build (edge structure is static within a call) ----
  hipMemsetAsync(cnt, 0, (size_t)N * 4 * 2, stream);
  k_hist<<<eb, 256, 0, stream>>>(col, cnt, E);
  k_scan1<<<nb, 256, 0, stream>>>(cnt, partial, bsum, N);
  k_scan2<<<1, 256, 0, stream>>>(bsum, boffs, nb);
  k_scan3<<<nb, 256, 0, stream>>>(partial, boffs, offs, N, E);
  k_scatter<<<eb, 256, 0, stream>>>(col, offs, cursor, perm, E);

  const float* hin = x;
  for (int layer = 0; layer < 3; ++layer) {
    hipMemsetAsync(rowsum, 0, (size_t)N * 4 * 3, stream);
    k_normalize<<<(N + 3) / 4, 256, 0, stream>>>(hin, bufA, N);
    k_edge_sim<<<(E + 15) / 16, 256, 0, stream>>>(bufA, row, col, simw, rowsum, degf, E);
    k_edge_weight<<<eb, 256, 0, stream>>>(row, col, simw, rowsum, degf, adj, gate, layer, colw, E);
    k_dinv<<<nb, 256, 0, stream>>>(colw, dinv, N);
    k_nrm<<<eb, 256, 0, stream>>>(row, col, simw, dinv, nrm, E);
    if (layer < 2) {
      const float* W = (layer == 0) ? W0 : W1;
      const float* b = (layer == 0) ? b0 : b1;
      k_gemm128<<<(N + 15) / 16, 256, 0, stream>>>(hin, W, bufB, N);
      k_agg128<<<N, 128, 0, stream>>>(bufB, nrm, perm, offs, row, b, bufC, 1);
      hin = bufC;
    } else {
      k_gemm40<<<(N + 7) / 8, 320, 0, stream>>>(hin, W2, bufB, N, C);
      k_agg40_lsm<<<N, 64, 0, stream>>>(bufB, nrm, perm, offs, row, b2, (float*)d_out, C);
    }
  }
}

// Round 2
// 905.077 us; speedup vs baseline: 1.3393x; 1.3393x over previous
//
#include <hip/hip_runtime.h>
#include <hip/hip_bf16.h>
#include <math.h>

#define F 128

// ---------------- row-normalize features: xn = x / max(||x||, eps) ----------
__global__ void k_normalize(const float* __restrict__ x, float* __restrict__ xn, int N) {
  int wid = (blockIdx.x * blockDim.x + threadIdx.x) >> 6;  // one wave per node
  int lane = threadIdx.x & 63;
  if (wid >= N) return;
  const float2* src = (const float2*)(x + (size_t)wid * F);
  float2 v = src[lane];
  float ss = v.x * v.x + v.y * v.y;
#pragma unroll
  for (int m = 32; m >= 1; m >>= 1) ss += __shfl_xor(ss, m);
  float inv = 1.0f / fmaxf(sqrtf(ss), 1e-12f);
  float2 o; o.x = v.x * inv; o.y = v.y * inv;
  ((float2*)(xn + (size_t)wid * F))[lane] = o;
}

// ---------------- CSR build: histogram, scan, scatter -----------------------
__global__ void k_hist(const int* __restrict__ idx, int* __restrict__ cnt, int E) {
  int e = blockIdx.x * blockDim.x + threadIdx.x;
  if (e < E) atomicAdd(cnt + idx[e], 1);
}

__global__ void k_scan1(const int* __restrict__ cnt, int* __restrict__ partial,
                        int* __restrict__ bsum, int N) {
  __shared__ int sm[256];
  int t = threadIdx.x;
  int i = blockIdx.x * 256 + t;
  int val = (i < N) ? cnt[i] : 0;
  sm[t] = val;
  __syncthreads();
  for (int off = 1; off < 256; off <<= 1) {
    int v = (t >= off) ? sm[t - off] : 0;
    __syncthreads();
    sm[t] += v;
    __syncthreads();
  }
  if (i < N) partial[i] = sm[t] - val;  // exclusive
  if (t == 255) bsum[blockIdx.x] = sm[255];
}

__global__ void k_scan2(const int* __restrict__ bsum, int* __restrict__ boffs, int nb) {
  __shared__ int sm[256];
  int t = threadIdx.x;
  int val = (t < nb) ? bsum[t] : 0;
  sm[t] = val;
  __syncthreads();
  for (int off = 1; off < 256; off <<= 1) {
    int v = (t >= off) ? sm[t - off] : 0;
    __syncthreads();
    sm[t] += v;
    __syncthreads();
  }
  if (t < nb) boffs[t] = sm[t] - val;  // exclusive
}

__global__ void k_scan3(const int* __restrict__ partial, const int* __restrict__ boffs,
                        int* __restrict__ offs, int N, int E) {
  int i = blockIdx.x * 256 + threadIdx.x;
  if (i < N) offs[i] = partial[i] + boffs[i >> 8];
  if (i == 0) offs[N] = E;
}

// scatter; optionally records inverse position (cpos[e] = CSR slot of edge e)
__global__ void k_scatter(const int* __restrict__ idx, const int* __restrict__ offs,
                          int* __restrict__ cursor, int* __restrict__ perm,
                          int* __restrict__ cpos, int E) {
  int e = blockIdx.x * blockDim.x + threadIdx.x;
  if (e >= E) return;
  int c = idx[e];
  int pos = offs[c] + atomicAdd(cursor + c, 1);
  perm[pos] = e;
  if (cpos) cpos[e] = pos;
}

// ---------------- fused per-row: cosine sims + threshold + rowsum/deg +
//                  final weight (+gating) + colw atomic ---------------------
// one block (128 thr = 8 groups x 16 lanes) per row; xn[row] cached in regs.
__global__ __launch_bounds__(128) void k_simw(
    const float* __restrict__ xn, const int* __restrict__ col,
    const int* __restrict__ perm_r, const int* __restrict__ offs_r,
    float* __restrict__ adj, float* __restrict__ wg, float* __restrict__ colw,
    const float* __restrict__ gate, int layer) {
  int r = blockIdx.x;
  int t = threadIdx.x;
  int p0 = offs_r[r], p1 = offs_r[r + 1];
  int ne = p1 - p0;                      // ~17 (Poisson(16) + self loop), <320
  __shared__ float xr[128];
  __shared__ float sims[320];
  __shared__ int scol[320];
  __shared__ float redv[2];
  __shared__ int redc[2];
  xr[t] = xn[(size_t)r * F + t];
  __syncthreads();
  int g = t >> 4, l = t & 15;
  float4 a0 = *(const float4*)(xr + l * 8);
  float4 a1 = *(const float4*)(xr + l * 8 + 4);
  for (int i = g; i < ne; i += 8) {
    int e = perm_r[p0 + i];
    int c = col[e];
    const float4* b = (const float4*)(xn + (size_t)c * F);
    float4 b0 = b[l * 2], b1 = b[l * 2 + 1];
    float s = a0.x * b0.x + a0.y * b0.y + a0.z * b0.z + a0.w * b0.w
            + a1.x * b1.x + a1.y * b1.y + a1.z * b1.z + a1.w * b1.w;
#pragma unroll
    for (int m = 8; m >= 1; m >>= 1) s += __shfl_xor(s, m);
    if (l == 0) {
      if (s < 0.1f || r == c) s = 0.0f;
      sims[i] = s;
      scol[i] = c;
    }
  }
  __syncthreads();
  // block reduce rowsum and deg (count of surviving sims)
  float v = 0.f; int cn = 0;
  for (int i = t; i < ne; i += 128) {
    float s = sims[i];
    v += s;
    cn += (s > 0.f) ? 1 : 0;
  }
#pragma unroll
  for (int m = 32; m >= 1; m >>= 1) { v += __shfl_xor(v, m); cn += __shfl_xor(cn, m); }
  if ((t & 63) == 0) { redv[t >> 6] = v; redc[t >> 6] = cn; }
  __syncthreads();
  float rs = redv[0] + redv[1];
  int deg = redc[0] + redc[1];
  float lam = 1.0f / (float)(deg + 1);
  float gg = (layer > 0) ? gate[layer - 1] : 0.f;
  for (int i = t; i < ne; i += 128) {
    int e = perm_r[p0 + i];
    int c = scol[i];
    float s = sims[i];
    float sn = (rs > 0.f) ? s / rs : 0.f;
    float w = (r == c) ? lam : sn;
    w = expf(w);                          // note: thresholded edges get exp(0)=1
    float wc;
    if (layer == 0) { adj[e] = w; wc = w; }
    else { wc = gg * adj[e] + (1.f - gg) * w; }
    wg[e] = wc;
    atomicAdd(colw + c, wc);
  }
}

__global__ void k_dinv(const float* __restrict__ colw, float* __restrict__ dinv, int N) {
  int i = blockIdx.x * blockDim.x + threadIdx.x;
  if (i >= N) return;
  float d = colw[i];
  dinv[i] = (d > 0.0f) ? rsqrtf(d) : 0.0f;
}

// pack (row, dinv[r]*w*dinv[c]) into the col-CSR slot -> agg reads 8B/edge seq
__global__ void k_prep(const int* __restrict__ row, const int* __restrict__ col,
                       const float* __restrict__ wg, const float* __restrict__ dinv,
                       const int* __restrict__ cpos, int2* __restrict__ packed, int E) {
  int e = blockIdx.x * blockDim.x + threadIdx.x;
  if (e >= E) return;
  int r = row[e];
  float nrm = dinv[r] * wg[e] * dinv[col[e]];  // dinv table 200KB -> L2 resident
  int2 rec; rec.x = r; rec.y = __float_as_int(nrm);
  packed[cpos[e]] = rec;
}

// ---------------- GEMM: out_bf16[M,128] = A[M,128] @ W[128,128] -------------
__global__ void k_gemm128(const float* __restrict__ A, const float* __restrict__ W,
                          __hip_bfloat16* __restrict__ out, int M) {
  __shared__ float As[16][128];
  int t = threadIdx.x;            // 256 threads
  int j = t & 127;
  int h = t >> 7;
  int n0 = blockIdx.x * 16;
  for (int i = t; i < 16 * 128; i += 256) {
    int nn = i >> 7, kk = i & 127;
    int gn = n0 + nn;
    As[nn][kk] = (gn < M) ? A[(size_t)gn * 128 + kk] : 0.f;
  }
  __syncthreads();
  float acc[8] = {0, 0, 0, 0, 0, 0, 0, 0};
  int base = h * 8;
  for (int k = 0; k < 128; ++k) {
    float wv = W[k * 128 + j];
#pragma unroll
    for (int i = 0; i < 8; ++i) acc[i] += As[base + i][k] * wv;
  }
#pragma unroll
  for (int i = 0; i < 8; ++i) {
    int gn = n0 + base + i;
    if (gn < M) out[(size_t)gn * 128 + j] = __float2bfloat16(acc[i]);
  }
}

// ---------------- GEMM: out[M,40] = A[M,128] @ W[128,40] (fp32) -------------
__global__ void k_gemm40(const float* __restrict__ A, const float* __restrict__ W,
                         float* __restrict__ out, int M, int C) {
  __shared__ float As[8][128];
  int t = threadIdx.x;            // 320 threads
  int n0 = blockIdx.x * 8;
  for (int i = t; i < 8 * 128; i += 320) {
    int nn = i >> 7, kk = i & 127;
    int gn = n0 + nn;
    As[nn][kk] = (gn < M) ? A[(size_t)gn * 128 + kk] : 0.f;
  }
  __syncthreads();
  int nn = t / 40;
  int j = t - nn * 40;
  int gn = n0 + nn;
  if (gn < M) {
    float acc = 0.f;
    for (int k = 0; k < 128; ++k) acc += As[nn][k] * W[k * C + j];
    out[(size_t)gn * C + j] = acc;
  }
}

// ---------------- aggregation (bf16 gather over packed col-CSR) -------------
__global__ __launch_bounds__(64) void k_agg128b(
    const __hip_bfloat162* __restrict__ hWb, const int2* __restrict__ packed,
    const int* __restrict__ offs_c, const float* __restrict__ bias,
    float* __restrict__ out, int relu) {
  int c = blockIdx.x;
  int t = threadIdx.x;            // 64 threads; thread t -> cols 2t, 2t+1
  int p0 = offs_c[c], p1 = offs_c[c + 1];
  float acc0 = bias[2 * t], acc1 = bias[2 * t + 1];
  for (int p = p0; p < p1; ++p) {
    int2 rec = packed[p];                         // broadcast (same addr all lanes)
    float w = __int_as_float(rec.y);
    __hip_bfloat162 hv = hWb[(size_t)rec.x * 64 + t];  // 256B coalesced gather
    acc0 += w * __bfloat162float(hv.x);
    acc1 += w * __bfloat162float(hv.y);
  }
  if (relu) { acc0 = fmaxf(acc0, 0.f); acc1 = fmaxf(acc1, 0.f); }
  float2 o; o.x = acc0; o.y = acc1;
  ((float2*)out)[(size_t)c * 64 + t] = o;
}

// ---------------- final aggregation + bias + log_softmax --------------------
__global__ __launch_bounds__(64) void k_agg40_lsm(
    const float* __restrict__ hW, const int2* __restrict__ packed,
    const int* __restrict__ offs_c, const float* __restrict__ bias,
    float* __restrict__ out, int C) {
  int c = blockIdx.x, j = threadIdx.x;  // 64 threads (one wave)
  int p0 = offs_c[c], p1 = offs_c[c + 1];
  bool act = j < C;
  float acc = act ? bias[j] : 0.f;
  for (int p = p0; p < p1; ++p) {
    int2 rec = packed[p];
    float w = __int_as_float(rec.y);
    if (act) acc += w * hW[(size_t)rec.x * C + j];
  }
  float v = act ? acc : -3.0e38f;
#pragma unroll
  for (int m = 32; m >= 1; m >>= 1) v = fmaxf(v, __shfl_xor(v, m));
  float ex = act ? expf(acc - v) : 0.f;
#pragma unroll
  for (int m = 32; m >= 1; m >>= 1) ex += __shfl_xor(ex, m);
  if (act) out[(size_t)c * C + j] = acc - v - logf(ex);
}

extern "C" void kernel_launch(void* const* d_in, const int* in_sizes, int n_in,
                              void* d_out, int out_size, void* d_ws, size_t ws_size,
                              hipStream_t stream) {
  const float* x    = (const float*)d_in[0];
  const float* gate = (const float*)d_in[1];
  const float* W0   = (const float*)d_in[2];
  const float* b0   = (const float*)d_in[3];
  const float* W1   = (const float*)d_in[4];
  const float* b1   = (const float*)d_in[5];
  const float* W2   = (const float*)d_in[6];
  const float* b2   = (const float*)d_in[7];
  const int* eidx   = (const int*)d_in[8];
  int N = in_sizes[0] / 128;
  int E = in_sizes[8] / 2;
  int C = in_sizes[7];  // 40
  const int* row = eidx;
  const int* col = eidx + E;

  char* ws = (char*)d_ws;
  size_t off = 0;
  auto alloc = [&](size_t bytes) {
    char* p = ws + off;
    off += (bytes + 255) & ~(size_t)255;
    return p;
  };
  float* xn     = (float*)alloc((size_t)N * 128 * 4);   // normalized feats
  float* bufC   = (float*)alloc((size_t)N * 128 * 4);   // layer activations
  __hip_bfloat16* hWb = (__hip_bfloat16*)alloc((size_t)N * 128 * 2);  // gemm out bf16
  float* hW2    = (float*)hWb;                           // layer-2 gemm out (aliases hWb; sequential use)
  float* adj    = (float*)alloc((size_t)E * 4);          // layer-0 weights (kept for gating)
  float* wg     = (float*)alloc((size_t)E * 4);          // gated edge weight
  int*   cpos   = (int*)alloc((size_t)E * 4);            // edge -> col-CSR slot
  int*   perm_c = (int*)alloc((size_t)E * 4);
  int*   perm_r = (int*)alloc((size_t)E * 4);
  int2*  packed = (int2*)alloc((size_t)E * 8);           // (row, nrm) per col-CSR slot
  int*   offs_c = (int*)alloc((size_t)(N + 1) * 4);
  int*   offs_r = (int*)alloc((size_t)(N + 1) * 4);
  int*   cnt    = (int*)alloc((size_t)N * 4 * 2);        // cnt + cursor
  int*   cursor = cnt + N;
  int*   partial= (int*)alloc((size_t)N * 4);
  int*   bsum   = (int*)alloc(1024);
  int*   boffs  = (int*)alloc(1024);
  float* colw   = (float*)alloc((size_t)N * 4);
  float* dinv   = (float*)alloc((size_t)N * 4);

  int nb = (N + 255) / 256;
  int eb = (E + 255) / 256;

  // ---- CSR by col (for aggregation), with inverse positions ----
  hipMemsetAsync(cnt, 0, (size_t)N * 4 * 2, stream);
  k_hist<<<eb, 256, 0, stream>>>(col, cnt, E);
  k_scan1<<<nb, 256, 0, stream>>>(cnt, partial, bsum, N);
  k_scan2<<<1, 256, 0, stream>>>(bsum, boffs, nb);
  k_scan3<<<nb, 256, 0, stream>>>(partial, boffs, offs_c, N, E);
  k_scatter<<<eb, 256, 0, stream>>>(col, offs_c, cursor, perm_c, cpos, E);

  // ---- CSR by row (for fused sim+weight) ----
  hipMemsetAsync(cnt, 0, (size_t)N * 4 * 2, stream);
  k_hist<<<eb, 256, 0, stream>>>(row, cnt, E);
  k_scan1<<<nb, 256, 0, stream>>>(cnt, partial, bsum, N);
  k_scan2<<<1, 256, 0, stream>>>(bsum, boffs, nb);
  k_scan3<<<nb, 256, 0, stream>>>(partial, boffs, offs_r, N, E);
  k_scatter<<<eb, 256, 0, stream>>>(row, offs_r, cursor, perm_r, (int*)nullptr, E);

  const float* hin = x;
  for (int layer = 0; layer < 3; ++layer) {
    hipMemsetAsync(colw, 0, (size_t)N * 4, stream);
    k_normalize<<<(N + 3) / 4, 256, 0, stream>>>(hin, xn, N);
    k_simw<<<N, 128, 0, stream>>>(xn, col, perm_r, offs_r, adj, wg, colw, gate, layer);
    k_dinv<<<nb, 256, 0, stream>>>(colw, dinv, N);
    k_prep<<<eb, 256, 0, stream>>>(row, col, wg, dinv, cpos, packed, E);
    if (layer < 2) {
      const float* W = (layer == 0) ? W0 : W1;
      const float* b = (layer == 0) ? b0 : b1;
      k_gemm128<<<(N + 15) / 16, 256, 0, stream>>>(hin, W, hWb, N);
      k_agg128b<<<N, 64, 0, stream>>>((const __hip_bfloat162*)hWb, packed, offs_c, b, bufC, 1);
      hin = bufC;
    } else {
      k_gemm40<<<(N + 7) / 8, 320, 0, stream>>>(hin, W2, hW2, N, C);
      k_agg40_lsm<<<N, 64, 0, stream>>>(hW2, packed, offs_c, b2, (float*)d_out, C);
    }
  }
}

// Round 3
// 847.220 us; speedup vs baseline: 1.4308x; 1.0683x over previous
//
#include <hip/hip_runtime.h>
#include <hip/hip_bf16.h>
#include <math.h>

#define F 128

typedef __attribute__((ext_vector_type(8))) unsigned short ushort8v;

__device__ __forceinline__ float bfu(unsigned short u) {
  return __uint_as_float(((unsigned)u) << 16);
}

// ------- row-normalize: xn = x/max(||x||,eps) (fp32 + bf16 copies) ----------
__global__ void k_normalize(const float* __restrict__ x, float* __restrict__ xn,
                            __hip_bfloat16* __restrict__ xnb, int N) {
  int wid = (blockIdx.x * blockDim.x + threadIdx.x) >> 6;  // one wave per node
  int lane = threadIdx.x & 63;
  if (wid >= N) return;
  const float2* src = (const float2*)(x + (size_t)wid * F);
  float2 v = src[lane];
  float ss = v.x * v.x + v.y * v.y;
#pragma unroll
  for (int m = 32; m >= 1; m >>= 1) ss += __shfl_xor(ss, m);
  float inv = 1.0f / fmaxf(sqrtf(ss), 1e-12f);
  float2 o; o.x = v.x * inv; o.y = v.y * inv;
  ((float2*)(xn + (size_t)wid * F))[lane] = o;
  __hip_bfloat162 ob;
  ob.x = __float2bfloat16(o.x); ob.y = __float2bfloat16(o.y);
  ((__hip_bfloat162*)(xnb + (size_t)wid * F))[lane] = ob;
}

// ---------------- CSR build: fused histograms, scan, scatter ----------------
__global__ void k_hist2(const int* __restrict__ row, const int* __restrict__ col,
                        int* __restrict__ cntr, int* __restrict__ cntc, int E) {
  int e = blockIdx.x * blockDim.x + threadIdx.x;
  if (e < E) { atomicAdd(cntr + row[e], 1); atomicAdd(cntc + col[e], 1); }
}

__global__ void k_scan1(const int* __restrict__ cnt, int* __restrict__ partial,
                        int* __restrict__ bsum, int N) {
  __shared__ int sm[256];
  int t = threadIdx.x;
  int i = blockIdx.x * 256 + t;
  int val = (i < N) ? cnt[i] : 0;
  sm[t] = val;
  __syncthreads();
  for (int off = 1; off < 256; off <<= 1) {
    int v = (t >= off) ? sm[t - off] : 0;
    __syncthreads();
    sm[t] += v;
    __syncthreads();
  }
  if (i < N) partial[i] = sm[t] - val;  // exclusive
  if (t == 255) bsum[blockIdx.x] = sm[255];
}

__global__ void k_scan2(const int* __restrict__ bsum, int* __restrict__ boffs, int nb) {
  __shared__ int sm[256];
  int t = threadIdx.x;
  int val = (t < nb) ? bsum[t] : 0;
  sm[t] = val;
  __syncthreads();
  for (int off = 1; off < 256; off <<= 1) {
    int v = (t >= off) ? sm[t - off] : 0;
    __syncthreads();
    sm[t] += v;
    __syncthreads();
  }
  if (t < nb) boffs[t] = sm[t] - val;  // exclusive
}

__global__ void k_scan3(const int* __restrict__ partial, const int* __restrict__ boffs,
                        int* __restrict__ offs, int N, int E) {
  int i = blockIdx.x * 256 + threadIdx.x;
  if (i < N) offs[i] = partial[i] + boffs[i >> 8];
  if (i == 0) offs[N] = E;
}

__global__ void k_scatter(const int* __restrict__ idx, const int* __restrict__ offs,
                          int* __restrict__ cursor, int* __restrict__ perm,
                          int* __restrict__ cpos, int E) {
  int e = blockIdx.x * blockDim.x + threadIdx.x;
  if (e >= E) return;
  int c = idx[e];
  int pos = offs[c] + atomicAdd(cursor + c, 1);
  perm[pos] = e;
  if (cpos) cpos[e] = pos;
}

// ------- fused per-row: bf16 cosine sims (fp32 recompute in guard band) +
//         threshold + rowsum/deg + final weight (+gating) + colw atomic -----
__global__ __launch_bounds__(128) void k_simw(
    const float* __restrict__ xn, const __hip_bfloat16* __restrict__ xnb,
    const int* __restrict__ col,
    const int* __restrict__ perm_r, const int* __restrict__ offs_r,
    float* __restrict__ adj, float* __restrict__ wg, float* __restrict__ colw,
    const float* __restrict__ gate, int layer) {
  int r = blockIdx.x;
  int t = threadIdx.x;
  int p0 = offs_r[r], p1 = offs_r[r + 1];
  int ne = p1 - p0;                      // ~17 (Poisson(16) + self loop), <320
  __shared__ float xr[128];
  __shared__ float sims[320];
  __shared__ int scol[320];
  __shared__ float redv[2];
  __shared__ int redc[2];
  xr[t] = xn[(size_t)r * F + t];
  __syncthreads();
  int g = t >> 4, l = t & 15;
  float4 a0 = *(const float4*)(xr + l * 8);
  float4 a1 = *(const float4*)(xr + l * 8 + 4);
  for (int i = g; i < ne; i += 8) {
    int e = perm_r[p0 + i];
    int c = col[e];
    ushort8v bv = *(const ushort8v*)(xnb + (size_t)c * F + l * 8);  // 16B gather
    float s = a0.x * bfu(bv[0]) + a0.y * bfu(bv[1]) + a0.z * bfu(bv[2]) + a0.w * bfu(bv[3])
            + a1.x * bfu(bv[4]) + a1.y * bfu(bv[5]) + a1.z * bfu(bv[6]) + a1.w * bfu(bv[7]);
#pragma unroll
    for (int m = 8; m >= 1; m >>= 1) s += __shfl_xor(s, m);
    bool self = (r == c);
    // bf16 worst-case dot error <= 2^-9 < 0.002; only the guard band can flip
    if (!self && fabsf(s - 0.1f) < 0.02f) {
      const float4* bp = (const float4*)(xn + (size_t)c * F);
      float4 b0 = bp[l * 2], b1 = bp[l * 2 + 1];
      float s2 = a0.x * b0.x + a0.y * b0.y + a0.z * b0.z + a0.w * b0.w
               + a1.x * b1.x + a1.y * b1.y + a1.z * b1.z + a1.w * b1.w;
#pragma unroll
      for (int m = 8; m >= 1; m >>= 1) s2 += __shfl_xor(s2, m);
      s = s2;
    }
    if (l == 0) {
      if (s < 0.1f || self) s = 0.0f;
      sims[i] = s;
      scol[i] = c;
    }
  }
  __syncthreads();
  // block reduce rowsum and deg (count of surviving sims)
  float v = 0.f; int cn = 0;
  for (int i = t; i < ne; i += 128) {
    float s = sims[i];
    v += s;
    cn += (s > 0.f) ? 1 : 0;
  }
#pragma unroll
  for (int m = 32; m >= 1; m >>= 1) { v += __shfl_xor(v, m); cn += __shfl_xor(cn, m); }
  if ((t & 63) == 0) { redv[t >> 6] = v; redc[t >> 6] = cn; }
  __syncthreads();
  float rs = redv[0] + redv[1];
  int deg = redc[0] + redc[1];
  float lam = 1.0f / (float)(deg + 1);
  float gg = (layer > 0) ? gate[layer - 1] : 0.f;
  for (int i = t; i < ne; i += 128) {
    int e = perm_r[p0 + i];
    int c = scol[i];
    float s = sims[i];
    float sn = (rs > 0.f) ? s / rs : 0.f;
    float w = (r == c) ? lam : sn;
    w = expf(w);                          // thresholded edges get exp(0)=1
    float wc;
    if (layer == 0) { adj[e] = w; wc = w; }
    else { wc = gg * adj[e] + (1.f - gg) * w; }
    wg[e] = wc;
    atomicAdd(colw + c, wc);
  }
}

__global__ void k_dinv(const float* __restrict__ colw, float* __restrict__ dinv, int N) {
  int i = blockIdx.x * blockDim.x + threadIdx.x;
  if (i >= N) return;
  float d = colw[i];
  dinv[i] = (d > 0.0f) ? rsqrtf(d) : 0.0f;
}

// pack (row, dinv[r]*w*dinv[c]) into the col-CSR slot -> agg reads 8B/edge seq
__global__ void k_prep(const int* __restrict__ row, const int* __restrict__ col,
                       const float* __restrict__ wg, const float* __restrict__ dinv,
                       const int* __restrict__ cpos, int2* __restrict__ packed, int E) {
  int e = blockIdx.x * blockDim.x + threadIdx.x;
  if (e >= E) return;
  int r = row[e];
  float nrm = dinv[r] * wg[e] * dinv[col[e]];  // dinv table 200KB -> L2 resident
  int2 rec; rec.x = r; rec.y = __float_as_int(nrm);
  packed[cpos[e]] = rec;
}

// ------ GEMM: out_bf16[M,128] = A[M,128] @ W[128,128], register-tiled -------
// block = 256 thr computes 32 nodes x 128 cols; thread = 8 nodes x 2 cols.
// As is k-major (pad 36 keeps 16B align; reads are wave-uniform broadcasts).
__global__ __launch_bounds__(256) void k_gemm128(const float* __restrict__ A,
                                                 const float* __restrict__ W,
                                                 __hip_bfloat16* __restrict__ out, int M) {
  __shared__ float As[128][36];
  int t = threadIdx.x;
  int n0 = blockIdx.x * 32;
  for (int i = t; i < 32 * 128; i += 256) {
    int nn = i >> 7, kk = i & 127;
    int gn = n0 + nn;
    As[kk][nn] = (gn < M) ? A[(size_t)gn * 128 + kk] : 0.f;
  }
  __syncthreads();
  int nb = (t >> 6) * 8;       // node base (wave-uniform -> LDS broadcast)
  int j2 = (t & 63) * 2;       // column pair
  float acc[8][2] = {};
  for (int k = 0; k < 128; ++k) {
    float4 a01 = *(const float4*)&As[k][nb];
    float4 a23 = *(const float4*)&As[k][nb + 4];
    float2 wv = *(const float2*)&W[k * 128 + j2];
    acc[0][0] += a01.x * wv.x; acc[0][1] += a01.x * wv.y;
    acc[1][0] += a01.y * wv.x; acc[1][1] += a01.y * wv.y;
    acc[2][0] += a01.z * wv.x; acc[2][1] += a01.z * wv.y;
    acc[3][0] += a01.w * wv.x; acc[3][1] += a01.w * wv.y;
    acc[4][0] += a23.x * wv.x; acc[4][1] += a23.x * wv.y;
    acc[5][0] += a23.y * wv.x; acc[5][1] += a23.y * wv.y;
    acc[6][0] += a23.z * wv.x; acc[6][1] += a23.z * wv.y;
    acc[7][0] += a23.w * wv.x; acc[7][1] += a23.w * wv.y;
  }
  __hip_bfloat162* o2 = (__hip_bfloat162*)out;
#pragma unroll
  for (int i = 0; i < 8; ++i) {
    int gn = n0 + nb + i;
    if (gn < M) {
      __hip_bfloat162 o;
      o.x = __float2bfloat16(acc[i][0]); o.y = __float2bfloat16(acc[i][1]);
      o2[(size_t)gn * 64 + (j2 >> 1)] = o;
    }
  }
}

// ------ GEMM: out_bf16[M,40] = A[M,128] @ W[128,40], register-tiled ---------
// block = 320 thr computes 64 nodes x 40 cols; thread = 8 nodes x 1 col.
__global__ __launch_bounds__(320) void k_gemm40(const float* __restrict__ A,
                                                const float* __restrict__ W,
                                                __hip_bfloat16* __restrict__ out,
                                                int M, int C) {
  __shared__ float As[128][68];
  int t = threadIdx.x;
  int n0 = blockIdx.x * 64;
  for (int i = t; i < 64 * 128; i += 320) {
    int nn = i >> 7, kk = i & 127;
    int gn = n0 + nn;
    As[kk][nn] = (gn < M) ? A[(size_t)gn * 128 + kk] : 0.f;
  }
  __syncthreads();
  int gq = t / 40;
  int jc = t - gq * 40;
  int nb = gq * 8;
  float acc[8] = {};
  for (int k = 0; k < 128; ++k) {
    float4 a01 = *(const float4*)&As[k][nb];
    float4 a23 = *(const float4*)&As[k][nb + 4];
    float wv = W[k * C + jc];
    acc[0] += a01.x * wv; acc[1] += a01.y * wv; acc[2] += a01.z * wv; acc[3] += a01.w * wv;
    acc[4] += a23.x * wv; acc[5] += a23.y * wv; acc[6] += a23.z * wv; acc[7] += a23.w * wv;
  }
#pragma unroll
  for (int i = 0; i < 8; ++i) {
    int gn = n0 + nb + i;
    if (gn < M) out[(size_t)gn * C + jc] = __float2bfloat16(acc[i]);
  }
}

// ---------------- aggregation (bf16 gather over packed col-CSR) -------------
__global__ __launch_bounds__(64) void k_agg128b(
    const __hip_bfloat162* __restrict__ hWb, const int2* __restrict__ packed,
    const int* __restrict__ offs_c, const float* __restrict__ bias,
    float* __restrict__ out, int relu) {
  int c = blockIdx.x;
  int t = threadIdx.x;            // 64 threads; thread t -> cols 2t, 2t+1
  int p0 = offs_c[c], p1 = offs_c[c + 1];
  float acc0 = bias[2 * t], acc1 = bias[2 * t + 1];
  for (int p = p0; p < p1; ++p) {
    int2 rec = packed[p];                         // broadcast (same addr all lanes)
    float w = __int_as_float(rec.y);
    __hip_bfloat162 hv = hWb[(size_t)rec.x * 64 + t];  // 256B coalesced gather
    acc0 += w * __bfloat162float(hv.x);
    acc1 += w * __bfloat162float(hv.y);
  }
  if (relu) { acc0 = fmaxf(acc0, 0.f); acc1 = fmaxf(acc1, 0.f); }
  float2 o; o.x = acc0; o.y = acc1;
  ((float2*)out)[(size_t)c * 64 + t] = o;
}

// ---------------- final aggregation + bias + log_softmax --------------------
__global__ __launch_bounds__(64) void k_agg40_lsm(
    const __hip_bfloat16* __restrict__ hW, const int2* __restrict__ packed,
    const int* __restrict__ offs_c, const float* __restrict__ bias,
    float* __restrict__ out, int C) {
  int c = blockIdx.x, j = threadIdx.x;  // 64 threads (one wave)
  int p0 = offs_c[c], p1 = offs_c[c + 1];
  bool act = j < C;
  float acc = act ? bias[j] : 0.f;
  for (int p = p0; p < p1; ++p) {
    int2 rec = packed[p];
    float w = __int_as_float(rec.y);
    if (act) acc += w * __bfloat162float(hW[(size_t)rec.x * C + j]);
  }
  float v = act ? acc : -3.0e38f;
#pragma unroll
  for (int m = 32; m >= 1; m >>= 1) v = fmaxf(v, __shfl_xor(v, m));
  float ex = act ? expf(acc - v) : 0.f;
#pragma unroll
  for (int m = 32; m >= 1; m >>= 1) ex += __shfl_xor(ex, m);
  if (act) out[(size_t)c * C + j] = acc - v - logf(ex);
}

extern "C" void kernel_launch(void* const* d_in, const int* in_sizes, int n_in,
                              void* d_out, int out_size, void* d_ws, size_t ws_size,
                              hipStream_t stream) {
  const float* x    = (const float*)d_in[0];
  const float* gate = (const float*)d_in[1];
  const float* W0   = (const float*)d_in[2];
  const float* b0   = (const float*)d_in[3];
  const float* W1   = (const float*)d_in[4];
  const float* b1   = (const float*)d_in[5];
  const float* W2   = (const float*)d_in[6];
  const float* b2   = (const float*)d_in[7];
  const int* eidx   = (const int*)d_in[8];
  int N = in_sizes[0] / 128;
  int E = in_sizes[8] / 2;
  int C = in_sizes[7];  // 40
  const int* row = eidx;
  const int* col = eidx + E;

  char* ws = (char*)d_ws;
  size_t off = 0;
  auto alloc = [&](size_t bytes) {
    char* p = ws + off;
    off += (bytes + 255) & ~(size_t)255;
    return p;
  };
  float* xn     = (float*)alloc((size_t)N * 128 * 4);   // normalized feats fp32
  __hip_bfloat16* xnb = (__hip_bfloat16*)alloc((size_t)N * 128 * 2);  // bf16 copy
  float* bufC   = (float*)alloc((size_t)N * 128 * 4);   // layer activations
  __hip_bfloat16* hWb = (__hip_bfloat16*)alloc((size_t)N * 128 * 2);  // gemm out bf16
  float* adj    = (float*)alloc((size_t)E * 4);          // layer-0 weights (gating)
  float* wg     = (float*)alloc((size_t)E * 4);          // gated edge weight
  int*   cpos   = (int*)alloc((size_t)E * 4);            // edge -> col-CSR slot
  int*   perm_c = (int*)alloc((size_t)E * 4);
  int*   perm_r = (int*)alloc((size_t)E * 4);
  int2*  packed = (int2*)alloc((size_t)E * 8);           // (row, nrm) per col-CSR slot
  int*   offs_c = (int*)alloc((size_t)(N + 1) * 4);
  int*   offs_r = (int*)alloc((size_t)(N + 1) * 4);
  int*   cnt    = (int*)alloc((size_t)N * 4 * 4);        // cnt_c,cur_c,cnt_r,cur_r
  int*   cur_c  = cnt + N;
  int*   cnt_r  = cnt + 2 * N;
  int*   cur_r  = cnt + 3 * N;
  int*   partial= (int*)alloc((size_t)N * 4);
  int*   bsum   = (int*)alloc(1024);
  int*   boffs  = (int*)alloc(1024);
  float* colw   = (float*)alloc((size_t)N * 4);
  float* dinv   = (float*)alloc((size_t)N * 4);

  int nb = (N + 255) / 256;
  int eb = (E + 255) / 256;

  // ---- CSR by col (aggregation) and by row (sims), one histogram pass ----
  hipMemsetAsync(cnt, 0, (size_t)N * 4 * 4, stream);
  k_hist2<<<eb, 256, 0, stream>>>(row, col, cnt_r, cnt, E);
  k_scan1<<<nb, 256, 0, stream>>>(cnt, partial, bsum, N);
  k_scan2<<<1, 256, 0, stream>>>(bsum, boffs, nb);
  k_scan3<<<nb, 256, 0, stream>>>(partial, boffs, offs_c, N, E);
  k_scatter<<<eb, 256, 0, stream>>>(col, offs_c, cur_c, perm_c, cpos, E);
  k_scan1<<<nb, 256, 0, stream>>>(cnt_r, partial, bsum, N);
  k_scan2<<<1, 256, 0, stream>>>(bsum, boffs, nb);
  k_scan3<<<nb, 256, 0, stream>>>(partial, boffs, offs_r, N, E);
  k_scatter<<<eb, 256, 0, stream>>>(row, offs_r, cur_r, perm_r, (int*)nullptr, E);

  const float* hin = x;
  for (int layer = 0; layer < 3; ++layer) {
    hipMemsetAsync(colw, 0, (size_t)N * 4, stream);
    k_normalize<<<(N + 3) / 4, 256, 0, stream>>>(hin, xn, xnb, N);
    k_simw<<<N, 128, 0, stream>>>(xn, xnb, col, perm_r, offs_r, adj, wg, colw, gate, layer);
    k_dinv<<<nb, 256, 0, stream>>>(colw, dinv, N);
    k_prep<<<eb, 256, 0, stream>>>(row, col, wg, dinv, cpos, packed, E);
    if (layer < 2) {
      const float* W = (layer == 0) ? W0 : W1;
      const float* b = (layer == 0) ? b0 : b1;
      k_gemm128<<<(N + 31) / 32, 256, 0, stream>>>(hin, W, hWb, N);
      k_agg128b<<<N, 64, 0, stream>>>((const __hip_bfloat162*)hWb, packed, offs_c, b, bufC, 1);
      hin = bufC;
    } else {
      k_gemm40<<<(N + 63) / 64, 320, 0, stream>>>(hin, W2, hWb, N, C);
      k_agg40_lsm<<<N, 64, 0, stream>>>(hWb, packed, offs_c, b2, (float*)d_out, C);
    }
  }
}

// Round 4
// 780.526 us; speedup vs baseline: 1.5530x; 1.0854x over previous
//
#include <hip/hip_runtime.h>
#include <hip/hip_bf16.h>
#include <math.h>

#define F 128

typedef __attribute__((ext_vector_type(8))) unsigned short ushort8v;

__device__ __forceinline__ float bfu(unsigned short u) {
  return __uint_as_float(((unsigned)u) << 16);
}

// ------- row-normalize: xn = x/max(||x||,eps) (fp32 + bf16 copies) ----------
__global__ void k_normalize(const float* __restrict__ x, float* __restrict__ xn,
                            __hip_bfloat16* __restrict__ xnb, int N) {
  int wid = (blockIdx.x * blockDim.x + threadIdx.x) >> 6;  // one wave per node
  int lane = threadIdx.x & 63;
  if (wid >= N) return;
  const float2* src = (const float2*)(x + (size_t)wid * F);
  float2 v = src[lane];
  float ss = v.x * v.x + v.y * v.y;
#pragma unroll
  for (int m = 32; m >= 1; m >>= 1) ss += __shfl_xor(ss, m);
  float inv = 1.0f / fmaxf(sqrtf(ss), 1e-12f);
  float2 o; o.x = v.x * inv; o.y = v.y * inv;
  ((float2*)(xn + (size_t)wid * F))[lane] = o;
  __hip_bfloat162 ob;
  ob.x = __float2bfloat16(o.x); ob.y = __float2bfloat16(o.y);
  ((__hip_bfloat162*)(xnb + (size_t)wid * F))[lane] = ob;
}

// ---------------- CSR build: fused histograms, scan, scatter ----------------
__global__ void k_hist2(const int* __restrict__ row, const int* __restrict__ col,
                        int* __restrict__ cntr, int* __restrict__ cntc, int E) {
  int e = blockIdx.x * blockDim.x + threadIdx.x;
  if (e < E) { atomicAdd(cntr + row[e], 1); atomicAdd(cntc + col[e], 1); }
}

__global__ void k_scan1(const int* __restrict__ cnt, int* __restrict__ partial,
                        int* __restrict__ bsum, int N) {
  __shared__ int sm[256];
  int t = threadIdx.x;
  int i = blockIdx.x * 256 + t;
  int val = (i < N) ? cnt[i] : 0;
  sm[t] = val;
  __syncthreads();
  for (int off = 1; off < 256; off <<= 1) {
    int v = (t >= off) ? sm[t - off] : 0;
    __syncthreads();
    sm[t] += v;
    __syncthreads();
  }
  if (i < N) partial[i] = sm[t] - val;  // exclusive
  if (t == 255) bsum[blockIdx.x] = sm[255];
}

__global__ void k_scan2(const int* __restrict__ bsum, int* __restrict__ boffs, int nb) {
  __shared__ int sm[256];
  int t = threadIdx.x;
  int val = (t < nb) ? bsum[t] : 0;
  sm[t] = val;
  __syncthreads();
  for (int off = 1; off < 256; off <<= 1) {
    int v = (t >= off) ? sm[t - off] : 0;
    __syncthreads();
    sm[t] += v;
    __syncthreads();
  }
  if (t < nb) boffs[t] = sm[t] - val;  // exclusive
}

__global__ void k_scan3(const int* __restrict__ partial, const int* __restrict__ boffs,
                        int* __restrict__ offs, int N, int E) {
  int i = blockIdx.x * 256 + threadIdx.x;
  if (i < N) offs[i] = partial[i] + boffs[i >> 8];
  if (i == 0) offs[N] = E;
}

__global__ void k_scatter(const int* __restrict__ idx, const int* __restrict__ offs,
                          int* __restrict__ cursor, int* __restrict__ perm,
                          int* __restrict__ pos_of_e, int E) {
  int e = blockIdx.x * blockDim.x + threadIdx.x;
  if (e >= E) return;
  int c = idx[e];
  int pos = offs[c] + atomicAdd(cursor + c, 1);
  perm[pos] = e;
  pos_of_e[e] = pos;
}

// ---- static index maps (built once; removes all per-layer random index IO):
//  colof_r[p]  = col of edge at row-CSR slot p      (simw reads sequentially)
//  rowof_c[pc] = row of edge at col-CSR slot pc     (prep reads sequentially)
//  colof_c[pc] = col of edge at col-CSR slot pc
//  c2r[pc]     = row-CSR slot of edge at col-CSR slot pc
__global__ void k_static(const int* __restrict__ row, const int* __restrict__ col,
                         const int* __restrict__ perm_r, const int* __restrict__ perm_c,
                         const int* __restrict__ rpos,
                         int* __restrict__ colof_r, int* __restrict__ rowof_c,
                         int* __restrict__ colof_c, int* __restrict__ c2r, int E) {
  int p = blockIdx.x * blockDim.x + threadIdx.x;
  if (p >= E) return;
  colof_r[p] = col[perm_r[p]];
  int e = perm_c[p];
  rowof_c[p] = row[e];
  colof_c[p] = col[e];
  c2r[p] = rpos[e];
}

// ------- fused per-row: bf16 cosine sims (fp32 recompute in guard band) +
//         threshold + rowsum/deg + weight (+gating) + colw atomic.
//         All per-edge IO is sequential in row-CSR slot order.
__global__ __launch_bounds__(128) void k_simw(
    const float* __restrict__ xn, const __hip_bfloat16* __restrict__ xnb,
    const int* __restrict__ colof_r, const int* __restrict__ offs_r,
    float* __restrict__ adjr, float* __restrict__ wgr, float* __restrict__ colw,
    const float* __restrict__ gate, int layer) {
  int r = blockIdx.x;
  int t = threadIdx.x;
  int p0 = offs_r[r], p1 = offs_r[r + 1];
  int ne = p1 - p0;                      // ~17 (Poisson(16) + self loop), <320
  __shared__ float xr[128];
  __shared__ float sims[320];
  __shared__ int scol[320];
  __shared__ float redv[2];
  __shared__ int redc[2];
  xr[t] = xn[(size_t)r * F + t];
  __syncthreads();
  int g = t >> 4, l = t & 15;
  float4 a0 = *(const float4*)(xr + l * 8);
  float4 a1 = *(const float4*)(xr + l * 8 + 4);
  for (int i = g; i < ne; i += 8) {
    int c = colof_r[p0 + i];             // broadcast within group
    ushort8v bv = *(const ushort8v*)(xnb + (size_t)c * F + l * 8);  // 16B gather
    float s = a0.x * bfu(bv[0]) + a0.y * bfu(bv[1]) + a0.z * bfu(bv[2]) + a0.w * bfu(bv[3])
            + a1.x * bfu(bv[4]) + a1.y * bfu(bv[5]) + a1.z * bfu(bv[6]) + a1.w * bfu(bv[7]);
#pragma unroll
    for (int m = 8; m >= 1; m >>= 1) s += __shfl_xor(s, m);
    bool self = (r == c);
    // bf16 worst-case dot error <= 2^-9 < 0.002; only the guard band can flip
    if (!self && fabsf(s - 0.1f) < 0.02f) {
      const float4* bp = (const float4*)(xn + (size_t)c * F);
      float4 b0 = bp[l * 2], b1 = bp[l * 2 + 1];
      float s2 = a0.x * b0.x + a0.y * b0.y + a0.z * b0.z + a0.w * b0.w
               + a1.x * b1.x + a1.y * b1.y + a1.z * b1.z + a1.w * b1.w;
#pragma unroll
      for (int m = 8; m >= 1; m >>= 1) s2 += __shfl_xor(s2, m);
      s = s2;
    }
    if (l == 0) {
      if (s < 0.1f || self) s = 0.0f;
      sims[i] = s;
      scol[i] = c;
    }
  }
  __syncthreads();
  // block reduce rowsum and deg (count of surviving sims)
  float v = 0.f; int cn = 0;
  for (int i = t; i < ne; i += 128) {
    float s = sims[i];
    v += s;
    cn += (s > 0.f) ? 1 : 0;
  }
#pragma unroll
  for (int m = 32; m >= 1; m >>= 1) { v += __shfl_xor(v, m); cn += __shfl_xor(cn, m); }
  if ((t & 63) == 0) { redv[t >> 6] = v; redc[t >> 6] = cn; }
  __syncthreads();
  float rs = redv[0] + redv[1];
  int deg = redc[0] + redc[1];
  float lam = 1.0f / (float)(deg + 1);
  float gg = (layer > 0) ? gate[layer - 1] : 0.f;
  for (int i = t; i < ne; i += 128) {
    int c = scol[i];
    float s = sims[i];
    float sn = (rs > 0.f) ? s / rs : 0.f;
    float w = (r == c) ? lam : sn;
    w = expf(w);                          // thresholded edges get exp(0)=1
    float wc;
    if (layer == 0) { adjr[p0 + i] = w; wc = w; }
    else { wc = gg * adjr[p0 + i] + (1.f - gg) * w; }
    wgr[p0 + i] = wc;                     // sequential write (no RMW scatter)
    atomicAdd(colw + c, wc);              // 200KB table, L2-resident
  }
}

// pack (row, dinv[r]*w*dinv[c]) sequentially in col-CSR order.
// dinv inlined via rsqrtf(colw) — identical values to a separate dinv pass.
__global__ void k_prep(const int* __restrict__ rowof_c, const int* __restrict__ colof_c,
                       const int* __restrict__ c2r, const float* __restrict__ wgr,
                       const float* __restrict__ colw, int2* __restrict__ packed, int E) {
  int pc = blockIdx.x * blockDim.x + threadIdx.x;
  if (pc >= E) return;
  int r = rowof_c[pc];
  float dr = colw[r];
  float dc = colw[colof_c[pc]];
  float dir_ = (dr > 0.f) ? rsqrtf(dr) : 0.f;
  float dic_ = (dc > 0.f) ? rsqrtf(dc) : 0.f;
  float nrm = dir_ * wgr[c2r[pc]] * dic_;   // wgr: random 4B read in 3.4MB L2 table
  int2 rec; rec.x = r; rec.y = __float_as_int(nrm);
  packed[pc] = rec;                          // sequential 8B write
}

// ------ GEMM: out_bf16[M,128] = A[M,128] @ W[128,128], register-tiled -------
__global__ __launch_bounds__(256) void k_gemm128(const float* __restrict__ A,
                                                 const float* __restrict__ W,
                                                 __hip_bfloat16* __restrict__ out, int M) {
  __shared__ float As[128][36];
  int t = threadIdx.x;
  int n0 = blockIdx.x * 32;
  for (int i = t; i < 32 * 128; i += 256) {
    int nn = i >> 7, kk = i & 127;
    int gn = n0 + nn;
    As[kk][nn] = (gn < M) ? A[(size_t)gn * 128 + kk] : 0.f;
  }
  __syncthreads();
  int nb = (t >> 6) * 8;       // node base (wave-uniform -> LDS broadcast)
  int j2 = (t & 63) * 2;       // column pair
  float acc[8][2] = {};
  for (int k = 0; k < 128; ++k) {
    float4 a01 = *(const float4*)&As[k][nb];
    float4 a23 = *(const float4*)&As[k][nb + 4];
    float2 wv = *(const float2*)&W[k * 128 + j2];
    acc[0][0] += a01.x * wv.x; acc[0][1] += a01.x * wv.y;
    acc[1][0] += a01.y * wv.x; acc[1][1] += a01.y * wv.y;
    acc[2][0] += a01.z * wv.x; acc[2][1] += a01.z * wv.y;
    acc[3][0] += a01.w * wv.x; acc[3][1] += a01.w * wv.y;
    acc[4][0] += a23.x * wv.x; acc[4][1] += a23.x * wv.y;
    acc[5][0] += a23.y * wv.x; acc[5][1] += a23.y * wv.y;
    acc[6][0] += a23.z * wv.x; acc[6][1] += a23.z * wv.y;
    acc[7][0] += a23.w * wv.x; acc[7][1] += a23.w * wv.y;
  }
  __hip_bfloat162* o2 = (__hip_bfloat162*)out;
#pragma unroll
  for (int i = 0; i < 8; ++i) {
    int gn = n0 + nb + i;
    if (gn < M) {
      __hip_bfloat162 o;
      o.x = __float2bfloat16(acc[i][0]); o.y = __float2bfloat16(acc[i][1]);
      o2[(size_t)gn * 64 + (j2 >> 1)] = o;
    }
  }
}

// ------ GEMM: out_bf16[M,40] = A[M,128] @ W[128,40], register-tiled ---------
__global__ __launch_bounds__(320) void k_gemm40(const float* __restrict__ A,
                                                const float* __restrict__ W,
                                                __hip_bfloat16* __restrict__ out,
                                                int M, int C) {
  __shared__ float As[128][68];
  int t = threadIdx.x;
  int n0 = blockIdx.x * 64;
  for (int i = t; i < 64 * 128; i += 320) {
    int nn = i >> 7, kk = i & 127;
    int gn = n0 + nn;
    As[kk][nn] = (gn < M) ? A[(size_t)gn * 128 + kk] : 0.f;
  }
  __syncthreads();
  int gq = t / 40;
  int jc = t - gq * 40;
  int nb = gq * 8;
  float acc[8] = {};
  for (int k = 0; k < 128; ++k) {
    float4 a01 = *(const float4*)&As[k][nb];
    float4 a23 = *(const float4*)&As[k][nb + 4];
    float wv = W[k * C + jc];
    acc[0] += a01.x * wv; acc[1] += a01.y * wv; acc[2] += a01.z * wv; acc[3] += a01.w * wv;
    acc[4] += a23.x * wv; acc[5] += a23.y * wv; acc[6] += a23.z * wv; acc[7] += a23.w * wv;
  }
#pragma unroll
  for (int i = 0; i < 8; ++i) {
    int gn = n0 + nb + i;
    if (gn < M) out[(size_t)gn * C + jc] = __float2bfloat16(acc[i]);
  }
}

// ---- aggregation + bias + relu, fused with normalize of the result row -----
__global__ __launch_bounds__(64) void k_agg_norm(
    const __hip_bfloat162* __restrict__ hWb, const int2* __restrict__ packed,
    const int* __restrict__ offs_c, const float* __restrict__ bias,
    float* __restrict__ out, float* __restrict__ xn, __hip_bfloat16* __restrict__ xnb) {
  int c = blockIdx.x;
  int t = threadIdx.x;            // 64 threads; thread t -> cols 2t, 2t+1
  int p0 = offs_c[c], p1 = offs_c[c + 1];
  float acc0 = bias[2 * t], acc1 = bias[2 * t + 1];
  int p = p0;
  for (; p + 2 <= p1; p += 2) {   // unroll x2: both gathers in flight
    int2 ra = packed[p], rb = packed[p + 1];
    __hip_bfloat162 ha = hWb[(size_t)ra.x * 64 + t];
    __hip_bfloat162 hb = hWb[(size_t)rb.x * 64 + t];
    float wa = __int_as_float(ra.y), wb = __int_as_float(rb.y);
    acc0 += wa * __bfloat162float(ha.x) + wb * __bfloat162float(hb.x);
    acc1 += wa * __bfloat162float(ha.y) + wb * __bfloat162float(hb.y);
  }
  if (p < p1) {
    int2 ra = packed[p];
    __hip_bfloat162 ha = hWb[(size_t)ra.x * 64 + t];
    float wa = __int_as_float(ra.y);
    acc0 += wa * __bfloat162float(ha.x);
    acc1 += wa * __bfloat162float(ha.y);
  }
  acc0 = fmaxf(acc0, 0.f); acc1 = fmaxf(acc1, 0.f);
  float2 o; o.x = acc0; o.y = acc1;
  ((float2*)out)[(size_t)c * 64 + t] = o;
  // fused row-normalize for the next layer's sims
  float ss = acc0 * acc0 + acc1 * acc1;
#pragma unroll
  for (int m = 32; m >= 1; m >>= 1) ss += __shfl_xor(ss, m);
  float inv = 1.0f / fmaxf(sqrtf(ss), 1e-12f);
  float2 on; on.x = acc0 * inv; on.y = acc1 * inv;
  ((float2*)xn)[(size_t)c * 64 + t] = on;
  __hip_bfloat162 ob;
  ob.x = __float2bfloat16(on.x); ob.y = __float2bfloat16(on.y);
  ((__hip_bfloat162*)xnb)[(size_t)c * 64 + t] = ob;
}

// ---------------- final aggregation + bias + log_softmax --------------------
__global__ __launch_bounds__(64) void k_agg40_lsm(
    const __hip_bfloat16* __restrict__ hW, const int2* __restrict__ packed,
    const int* __restrict__ offs_c, const float* __restrict__ bias,
    float* __restrict__ out, int C) {
  int c = blockIdx.x, j = threadIdx.x;  // 64 threads (one wave)
  int p0 = offs_c[c], p1 = offs_c[c + 1];
  bool act = j < C;
  float acc = act ? bias[j] : 0.f;
  for (int p = p0; p < p1; ++p) {
    int2 rec = packed[p];
    float w = __int_as_float(rec.y);
    if (act) acc += w * __bfloat162float(hW[(size_t)rec.x * C + j]);
  }
  float v = act ? acc : -3.0e38f;
#pragma unroll
  for (int m = 32; m >= 1; m >>= 1) v = fmaxf(v, __shfl_xor(v, m));
  float ex = act ? expf(acc - v) : 0.f;
#pragma unroll
  for (int m = 32; m >= 1; m >>= 1) ex += __shfl_xor(ex, m);
  if (act) out[(size_t)c * C + j] = acc - v - logf(ex);
}

extern "C" void kernel_launch(void* const* d_in, const int* in_sizes, int n_in,
                              void* d_out, int out_size, void* d_ws, size_t ws_size,
                              hipStream_t stream) {
  const float* x    = (const float*)d_in[0];
  const float* gate = (const float*)d_in[1];
  const float* W0   = (const float*)d_in[2];
  const float* b0   = (const float*)d_in[3];
  const float* W1   = (const float*)d_in[4];
  const float* b1   = (const float*)d_in[5];
  const float* W2   = (const float*)d_in[6];
  const float* b2   = (const float*)d_in[7];
  const int* eidx   = (const int*)d_in[8];
  int N = in_sizes[0] / 128;
  int E = in_sizes[8] / 2;
  int C = in_sizes[7];  // 40
  const int* row = eidx;
  const int* col = eidx + E;

  char* ws = (char*)d_ws;
  size_t off = 0;
  auto alloc = [&](size_t bytes) {
    char* p = ws + off;
    off += (bytes + 255) & ~(size_t)255;
    return p;
  };
  float* xn     = (float*)alloc((size_t)N * 128 * 4);
  __hip_bfloat16* xnb = (__hip_bfloat16*)alloc((size_t)N * 128 * 2);
  float* bufC   = (float*)alloc((size_t)N * 128 * 4);
  __hip_bfloat16* hWb = (__hip_bfloat16*)alloc((size_t)N * 128 * 2);
  float* adjr   = (float*)alloc((size_t)E * 4);   // layer-0 weights, row-CSR order
  float* wgr    = (float*)alloc((size_t)E * 4);   // gated weight, row-CSR order
  int*   cpos   = (int*)alloc((size_t)E * 4);
  int*   rpos   = (int*)alloc((size_t)E * 4);
  int*   perm_c = (int*)alloc((size_t)E * 4);
  int*   perm_r = (int*)alloc((size_t)E * 4);
  int2*  packed = (int2*)alloc((size_t)E * 8);
  int*   colof_r= (int*)alloc((size_t)E * 4);
  int*   rowof_c= (int*)alloc((size_t)E * 4);
  int*   colof_c= (int*)alloc((size_t)E * 4);
  int*   c2r    = (int*)alloc((size_t)E * 4);
  int*   offs_c = (int*)alloc((size_t)(N + 1) * 4);
  int*   offs_r = (int*)alloc((size_t)(N + 1) * 4);
  int*   cnt    = (int*)alloc((size_t)N * 4 * 4); // cnt_c,cur_c,cnt_r,cur_r
  int*   cur_c  = cnt + N;
  int*   cnt_r  = cnt + 2 * N;
  int*   cur_r  = cnt + 3 * N;
  int*   partial= (int*)alloc((size_t)N * 4);
  int*   bsum   = (int*)alloc(1024);
  int*   boffs  = (int*)alloc(1024);
  float* colw   = (float*)alloc((size_t)N * 4);

  int nb = (N + 255) / 256;
  int eb = (E + 255) / 256;

  // ---- build col-CSR + row-CSR + static index maps (one-time per call) ----
  hipMemsetAsync(cnt, 0, (size_t)N * 4 * 4, stream);
  k_hist2<<<eb, 256, 0, stream>>>(row, col, cnt_r, cnt, E);
  k_scan1<<<nb, 256, 0, stream>>>(cnt, partial, bsum, N);
  k_scan2<<<1, 256, 0, stream>>>(bsum, boffs, nb);
  k_scan3<<<nb, 256, 0, stream>>>(partial, boffs, offs_c, N, E);
  k_scatter<<<eb, 256, 0, stream>>>(col, offs_c, cur_c, perm_c, cpos, E);
  k_scan1<<<nb, 256, 0, stream>>>(cnt_r, partial, bsum, N);
  k_scan2<<<1, 256, 0, stream>>>(bsum, boffs, nb);
  k_scan3<<<nb, 256, 0, stream>>>(partial, boffs, offs_r, N, E);
  k_scatter<<<eb, 256, 0, stream>>>(row, offs_r, cur_r, perm_r, rpos, E);
  k_static<<<eb, 256, 0, stream>>>(row, col, perm_r, perm_c, rpos,
                                   colof_r, rowof_c, colof_c, c2r, E);

  for (int layer = 0; layer < 3; ++layer) {
    hipMemsetAsync(colw, 0, (size_t)N * 4, stream);
    if (layer == 0) k_normalize<<<(N + 3) / 4, 256, 0, stream>>>(x, xn, xnb, N);
    // (layers 1-2: xn/xnb already produced by previous k_agg_norm)
    k_simw<<<N, 128, 0, stream>>>(xn, xnb, colof_r, offs_r, adjr, wgr, colw, gate, layer);
    k_prep<<<eb, 256, 0, stream>>>(rowof_c, colof_c, c2r, wgr, colw, packed, E);
    const float* hin = (layer == 0) ? x : bufC;
    if (layer < 2) {
      const float* W = (layer == 0) ? W0 : W1;
      const float* b = (layer == 0) ? b0 : b1;
      k_gemm128<<<(N + 31) / 32, 256, 0, stream>>>(hin, W, hWb, N);
      k_agg_norm<<<N, 64, 0, stream>>>((const __hip_bfloat162*)hWb, packed, offs_c, b,
                                       bufC, xn, xnb);
    } else {
      k_gemm40<<<(N + 63) / 64, 320, 0, stream>>>(hin, W2, hWb, N, C);
      k_agg40_lsm<<<N, 64, 0, stream>>>(hWb, packed, offs_c, b2, (float*)d_out, C);
    }
  }
}